// Round 1
// baseline (2600.270 us; speedup 1.0000x reference)
//
#include <hip/hip_runtime.h>
#include <math.h>

#define B_    4
#define N_    2048
#define DIM_  1024
#define H_    16
#define DH_   64
#define HID_  1024
#define SCALE_ 0.125f

// ---------------------------------------------------------------------------
// Generic fp32 GEMM: C[M,N] = A[M,K] @ Bm[K,N] (+ bias), row-major.
// 64x64 block tile, BK=16, 256 threads, 4x4 microtile per thread.
// ---------------------------------------------------------------------------
__global__ __launch_bounds__(256) void gemm_f32(const float* __restrict__ A,
                                                const float* __restrict__ Bm,
                                                const float* __restrict__ bias,
                                                float* __restrict__ C,
                                                int M, int N, int K) {
    const int BK = 16;
    __shared__ float as[16][68];  // as[kk][r]  (A tile transposed), stride 68 -> 16B aligned rows
    __shared__ float bs[16][68];  // bs[kk][c]

    int tid = threadIdx.x;
    int tr = tid >> 4;        // 0..15
    int tc = tid & 15;        // 0..15
    int bm = blockIdx.y * 64;
    int bn = blockIdx.x * 64;

    float acc[4][4] = {};

    for (int k0 = 0; k0 < K; k0 += BK) {
        __syncthreads();
        {   // A tile: 64 rows x 16 k. thread: r = tid>>2, kk4 = (tid&3)*4
            int r = tid >> 2, kk4 = (tid & 3) * 4;
            float4 g = *(const float4*)&A[(size_t)(bm + r) * K + k0 + kk4];
            as[kk4 + 0][r] = g.x;
            as[kk4 + 1][r] = g.y;
            as[kk4 + 2][r] = g.z;
            as[kk4 + 3][r] = g.w;
        }
        {   // B tile: 16 rows x 64 cols. thread: kk = tid>>4, c4 = (tid&15)*4
            int kk = tid >> 4, c4 = (tid & 15) * 4;
            *(float4*)&bs[kk][c4] =
                *(const float4*)&Bm[(size_t)(k0 + kk) * N + bn + c4];
        }
        __syncthreads();

        #pragma unroll
        for (int kk = 0; kk < BK; kk++) {
            float4 a4 = *(const float4*)&as[kk][tr * 4];
            float4 b4 = *(const float4*)&bs[kk][tc * 4];
            float a[4] = {a4.x, a4.y, a4.z, a4.w};
            float b[4] = {b4.x, b4.y, b4.z, b4.w};
            #pragma unroll
            for (int i = 0; i < 4; i++)
                #pragma unroll
                for (int j = 0; j < 4; j++)
                    acc[i][j] += a[i] * b[j];
        }
    }

    float bv[4] = {0.f, 0.f, 0.f, 0.f};
    if (bias != nullptr) {
        #pragma unroll
        for (int j = 0; j < 4; j++) bv[j] = bias[bn + tc * 4 + j];
    }
    #pragma unroll
    for (int i = 0; i < 4; i++) {
        int row = bm + tr * 4 + i;
        float4 o;
        o.x = acc[i][0] + bv[0];
        o.y = acc[i][1] + bv[1];
        o.z = acc[i][2] + bv[2];
        o.w = acc[i][3] + bv[3];
        *(float4*)&C[(size_t)row * N + bn + tc * 4] = o;
    }
}

// ---------------------------------------------------------------------------
// Column softmax stats: invl[bh, j] = 1 / sum_i exp(scale * q_i . k_j)
// Softmax is over the QUERY axis (axis=2 in the reference).
// Grid: (N/64, B*H). Block: 256. Thread owns jl in {tc+16u}, il in {tr+16u}.
// ---------------------------------------------------------------------------
__global__ __launch_bounds__(256) void attn_stats(const float* __restrict__ qkv,
                                                  float* __restrict__ invl) {
    int bh = blockIdx.y;
    int b = bh >> 4, h = bh & 15;
    int j0 = blockIdx.x * 64;

    __shared__ float kt[64][68];
    __shared__ float qt[64][68];
    __shared__ float red[16][64];

    int tid = threadIdx.x;
    int tr = tid >> 4, tc = tid & 15;

    const int rs = 3 * HID_;
    const float* qbase = qkv + (size_t)b * N_ * rs + h * DH_;
    const float* kbase = qbase + HID_;

    // Load K tile once (64 rows x 64 dims), float4.
    for (int idx = tid; idx < 64 * 16; idx += 256) {
        int r = idx >> 4, d4 = (idx & 15) * 4;
        *(float4*)&kt[r][d4] = *(const float4*)&kbase[(size_t)(j0 + r) * rs + d4];
    }

    float lsum[4] = {0.f, 0.f, 0.f, 0.f};

    for (int i0 = 0; i0 < N_; i0 += 64) {
        __syncthreads();
        for (int idx = tid; idx < 64 * 16; idx += 256) {
            int r = idx >> 4, d4 = (idx & 15) * 4;
            *(float4*)&qt[r][d4] = *(const float4*)&qbase[(size_t)(i0 + r) * rs + d4];
        }
        __syncthreads();

        float s[4][4] = {};
        #pragma unroll
        for (int d = 0; d < 64; d += 4) {
            float4 q4[4], k4[4];
            #pragma unroll
            for (int u = 0; u < 4; u++) q4[u] = *(const float4*)&qt[tr + 16 * u][d];
            #pragma unroll
            for (int u = 0; u < 4; u++) k4[u] = *(const float4*)&kt[tc + 16 * u][d];
            #pragma unroll
            for (int i = 0; i < 4; i++)
                #pragma unroll
                for (int j = 0; j < 4; j++)
                    s[i][j] += q4[i].x * k4[j].x + q4[i].y * k4[j].y +
                               q4[i].z * k4[j].z + q4[i].w * k4[j].w;
        }
        #pragma unroll
        for (int i = 0; i < 4; i++)
            #pragma unroll
            for (int j = 0; j < 4; j++)
                lsum[j] += __expf(s[i][j] * SCALE_);
    }

    __syncthreads();
    #pragma unroll
    for (int j = 0; j < 4; j++) red[tr][tc + 16 * j] = lsum[j];
    __syncthreads();
    if (tid < 64) {
        float l = 0.f;
        #pragma unroll
        for (int r = 0; r < 16; r++) l += red[r][tid];
        invl[(size_t)bh * N_ + j0 + tid] = 1.0f / l;
    }
}

// ---------------------------------------------------------------------------
// y[b, i, h*64+d] = sum_j exp(scale * q_i . k_j) * invl_j * v[j, d]
// Grid: (N/64, B*H). Block: 256. Flash-style over j tiles, no rescale needed.
// ---------------------------------------------------------------------------
__global__ __launch_bounds__(256) void attn_apply(const float* __restrict__ qkv,
                                                  const float* __restrict__ invl,
                                                  float* __restrict__ y) {
    int bh = blockIdx.y;
    int b = bh >> 4, h = bh & 15;
    int i0 = blockIdx.x * 64;

    __shared__ float qt[64][68];
    __shared__ float kt[64][68];
    __shared__ float vt[64][68];
    __shared__ float pt[64][80];   // stride 80 -> 2-way max on scatter writes
    __shared__ float cj[64];

    int tid = threadIdx.x;
    int tr = tid >> 4, tc = tid & 15;

    const int rs = 3 * HID_;
    const float* qbase = qkv + (size_t)b * N_ * rs + h * DH_;
    const float* kbase = qbase + HID_;
    const float* vbase = qbase + 2 * HID_;

    // Load Q tile once.
    for (int idx = tid; idx < 64 * 16; idx += 256) {
        int r = idx >> 4, d4 = (idx & 15) * 4;
        *(float4*)&qt[r][d4] = *(const float4*)&qbase[(size_t)(i0 + r) * rs + d4];
    }

    float acc[4][4] = {};

    for (int j0 = 0; j0 < N_; j0 += 64) {
        __syncthreads();
        for (int idx = tid; idx < 64 * 16; idx += 256) {
            int r = idx >> 4, d4 = (idx & 15) * 4;
            *(float4*)&kt[r][d4] = *(const float4*)&kbase[(size_t)(j0 + r) * rs + d4];
            *(float4*)&vt[r][d4] = *(const float4*)&vbase[(size_t)(j0 + r) * rs + d4];
        }
        if (tid < 64) cj[tid] = invl[(size_t)bh * N_ + j0 + tid];
        __syncthreads();

        // S tile: thread owns il = tr+16i, jl = tc+16j.
        float s[4][4] = {};
        #pragma unroll
        for (int d = 0; d < 64; d += 4) {
            float4 q4[4], k4[4];
            #pragma unroll
            for (int u = 0; u < 4; u++) q4[u] = *(const float4*)&qt[tr + 16 * u][d];
            #pragma unroll
            for (int u = 0; u < 4; u++) k4[u] = *(const float4*)&kt[tc + 16 * u][d];
            #pragma unroll
            for (int i = 0; i < 4; i++)
                #pragma unroll
                for (int j = 0; j < 4; j++)
                    s[i][j] += q4[i].x * k4[j].x + q4[i].y * k4[j].y +
                               q4[i].z * k4[j].z + q4[i].w * k4[j].w;
        }
        #pragma unroll
        for (int i = 0; i < 4; i++)
            #pragma unroll
            for (int j = 0; j < 4; j++)
                pt[tr + 16 * i][tc + 16 * j] = __expf(s[i][j] * SCALE_) * cj[tc + 16 * j];
        __syncthreads();

        // y tile += P @ V. Thread owns il = tr+16i, d' = tc*4..tc*4+3.
        for (int j = 0; j < 64; j += 4) {
            float pr[4][4];
            #pragma unroll
            for (int i = 0; i < 4; i++) {
                float4 p4 = *(const float4*)&pt[tr + 16 * i][j];
                pr[i][0] = p4.x; pr[i][1] = p4.y; pr[i][2] = p4.z; pr[i][3] = p4.w;
            }
            #pragma unroll
            for (int jj = 0; jj < 4; jj++) {
                float4 bv = *(const float4*)&vt[j + jj][tc * 4];
                #pragma unroll
                for (int i = 0; i < 4; i++) {
                    acc[i][0] += pr[i][jj] * bv.x;
                    acc[i][1] += pr[i][jj] * bv.y;
                    acc[i][2] += pr[i][jj] * bv.z;
                    acc[i][3] += pr[i][jj] * bv.w;
                }
            }
        }
    }

    // Write y in [B*N, HID] layout so the out-projection is a plain GEMM.
    #pragma unroll
    for (int i = 0; i < 4; i++) {
        float4 o;
        o.x = acc[i][0]; o.y = acc[i][1]; o.z = acc[i][2]; o.w = acc[i][3];
        *(float4*)&y[((size_t)b * N_ + i0 + tr + 16 * i) * HID_ + h * DH_ + tc * 4] = o;
    }
}

// ---------------------------------------------------------------------------
extern "C" void kernel_launch(void* const* d_in, const int* in_sizes, int n_in,
                              void* d_out, int out_size, void* d_ws, size_t ws_size,
                              hipStream_t stream) {
    (void)in_sizes; (void)n_in; (void)out_size; (void)ws_size;

    const float* x     = (const float*)d_in[0];
    const float* w_qkv = (const float*)d_in[1];
    const float* w_out = (const float*)d_in[2];
    const float* b_out = (const float*)d_in[3];
    float* out = (float*)d_out;

    float* qkv  = (float*)d_ws;                                  // [B*N, 3*HID] = 100.7 MB
    float* invl = qkv + (size_t)(B_ * N_) * (3 * HID_);          // [B*H, N]     = 0.5 MB
    float* y    = invl + (size_t)(B_ * H_) * N_;                 // [B*N, HID]   = 33.5 MB

    // 1) qkv projection: [8192,1024] @ [1024,3072]
    gemm_f32<<<dim3((3 * HID_) / 64, (B_ * N_) / 64), 256, 0, stream>>>(
        x, w_qkv, nullptr, qkv, B_ * N_, 3 * HID_, DIM_);

    // 2) per-key softmax denominators (softmax over query axis)
    attn_stats<<<dim3(N_ / 64, B_ * H_), 256, 0, stream>>>(qkv, invl);

    // 3) apply attention: y = (exp(S) * invl_col) @ V
    attn_apply<<<dim3(N_ / 64, B_ * H_), 256, 0, stream>>>(qkv, invl, y);

    // 4) output projection + bias: [8192,1024] @ [1024,1024]
    gemm_f32<<<dim3(DIM_ / 64, (B_ * N_) / 64), 256, 0, stream>>>(
        y, w_out, b_out, out, B_ * N_, DIM_, HID_);
}

// Round 3
// 461.447 us; speedup vs baseline: 5.6350x; 5.6350x over previous
//
#include <hip/hip_runtime.h>
#include <math.h>
#include <stdint.h>

#define B_    4
#define N_    2048
#define DIM_  1024
#define H_    16
#define DH_   64
#define HID_  1024
#define RS_   3072          // qkv row stride (3*HID)
#define SCALE_ 0.125f

typedef unsigned short u16;
typedef unsigned int   u32;
typedef short  bf16x8 __attribute__((ext_vector_type(8)));   // 8 bf16 = 4 VGPRs (MFMA A/B frag)
typedef u16    u16x8  __attribute__((ext_vector_type(8)));   // 16B vector for bf16 data movement
typedef float  f32x4  __attribute__((ext_vector_type(4)));   // MFMA C/D frag

__device__ inline u16 f2b(float x) {   // fp32 -> bf16, round-to-nearest-even
    u32 u = __float_as_uint(x);
    return (u16)((u + 0x7fffu + ((u >> 16) & 1u)) >> 16);
}

// ---------------------------------------------------------------------------
// Elementwise fp32 -> bf16 cast (x). 8 elems/thread.
// ---------------------------------------------------------------------------
__global__ __launch_bounds__(256) void cast_bf16(const float* __restrict__ in,
                                                 u16* __restrict__ out, int n) {
    int i = (blockIdx.x * 256 + threadIdx.x) * 8;
    if (i >= n) return;
    float4 a = *(const float4*)&in[i];
    float4 b = *(const float4*)&in[i + 4];
    u16x8 p;
    p[0] = f2b(a.x); p[1] = f2b(a.y); p[2] = f2b(a.z); p[3] = f2b(a.w);
    p[4] = f2b(b.x); p[5] = f2b(b.y); p[6] = f2b(b.z); p[7] = f2b(b.w);
    *(u16x8*)&out[i] = p;
}

// ---------------------------------------------------------------------------
// W[K][Nn] fp32 -> Wt[Nn][K] bf16 (64x64 tiles).
// ---------------------------------------------------------------------------
__global__ __launch_bounds__(256) void transpose_cast(const float* __restrict__ W,
                                                      u16* __restrict__ Wt,
                                                      int K, int Nn) {
    __shared__ float t[64][65];
    const int tid = threadIdx.x;
    const int k0 = blockIdx.y * 64, n0 = blockIdx.x * 64;
    for (int idx = tid; idx < 64 * 16; idx += 256) {
        int r = idx >> 4, c4 = (idx & 15) * 4;
        float4 g = *(const float4*)&W[(size_t)(k0 + r) * Nn + n0 + c4];
        t[r][c4] = g.x; t[r][c4 + 1] = g.y; t[r][c4 + 2] = g.z; t[r][c4 + 3] = g.w;
    }
    __syncthreads();
    for (int idx = tid; idx < 64 * 8; idx += 256) {
        int n = idx >> 3, k8 = (idx & 7) * 8;
        u16x8 p;
        #pragma unroll
        for (int u = 0; u < 8; u++) p[u] = f2b(t[k8 + u][n]);
        *(u16x8*)&Wt[(size_t)(n0 + n) * K + k0 + k8] = p;
    }
}

// ---------------------------------------------------------------------------
// Per-head V transpose: vT[bh][d][j] = qkv_bf16[b, j, 2*HID + h*64 + d]
// ---------------------------------------------------------------------------
__global__ __launch_bounds__(256) void build_vT(const u16* __restrict__ qkvb,
                                                u16* __restrict__ vT) {
    __shared__ u16 t[64 * 72];
    const int tid = threadIdx.x;
    const int bh = blockIdx.y, b = bh >> 4, h = bh & 15;
    const int j0 = blockIdx.x * 64;
    const u16* vbase = qkvb + (size_t)b * N_ * RS_ + 2 * HID_ + h * DH_;
    // full 64x64 bf16 tile = 512 chunks of 16B
    for (int idx = tid; idx < 512; idx += 256) {
        int r = idx >> 3, d8 = (idx & 7) * 8;
        *(u16x8*)&t[r * 72 + d8] = *(const u16x8*)&vbase[(size_t)(j0 + r) * RS_ + d8];
    }
    __syncthreads();
    {
        int d = tid >> 2, j16 = (tid & 3) * 16;
        u16x8 p0, p1;
        #pragma unroll
        for (int u = 0; u < 8; u++) {
            p0[u] = t[(j16 + u) * 72 + d];
            p1[u] = t[(j16 + 8 + u) * 72 + d];
        }
        size_t o = ((size_t)bh * DH_ + d) * N_ + j0 + j16;
        *(u16x8*)&vT[o] = p0;
        *(u16x8*)&vT[o + 8] = p1;
    }
}

// ---------------------------------------------------------------------------
// GEMM (BT form): C[M][Nn] = A[M][K] . Bt[Nn][K]^T (+bias), bf16 in, MFMA.
// 128x128 tile, BK=32, 256 thr (4 waves in 2x2), 4x4 16x16x32 tiles/wave.
// ---------------------------------------------------------------------------
template<int BF16OUT>
__global__ __launch_bounds__(256) void gemm_bt(const u16* __restrict__ A,
                                               const u16* __restrict__ Bt,
                                               const float* __restrict__ bias,
                                               void* __restrict__ Cout,
                                               int M, int Nn, int K) {
    __shared__ u16 at[128 * 32];
    __shared__ u16 bt[128 * 32];
    const int tid = threadIdx.x;
    const int lane = tid & 63, wave = tid >> 6;
    const int wr = wave >> 1, wc = wave & 1;
    const int mlane = lane & 15, quad = lane >> 4;
    const int m0 = blockIdx.y * 128, n0 = blockIdx.x * 128;
    const int r = tid >> 2, kc = (tid & 3) * 8;

    f32x4 acc[4][4] = {};

    for (int k0 = 0; k0 < K; k0 += 32) {
        __syncthreads();
        *(u16x8*)&at[r * 32 + kc]        = *(const u16x8*)&A[(size_t)(m0 + r) * K + k0 + kc];
        *(u16x8*)&at[(r + 64) * 32 + kc] = *(const u16x8*)&A[(size_t)(m0 + r + 64) * K + k0 + kc];
        *(u16x8*)&bt[r * 32 + kc]        = *(const u16x8*)&Bt[(size_t)(n0 + r) * K + k0 + kc];
        *(u16x8*)&bt[(r + 64) * 32 + kc] = *(const u16x8*)&Bt[(size_t)(n0 + r + 64) * K + k0 + kc];
        __syncthreads();

        bf16x8 af[4], bf[4];
        #pragma unroll
        for (int rt = 0; rt < 4; rt++)
            af[rt] = *(const bf16x8*)&at[(wr * 64 + rt * 16 + mlane) * 32 + quad * 8];
        #pragma unroll
        for (int ct = 0; ct < 4; ct++)
            bf[ct] = *(const bf16x8*)&bt[(wc * 64 + ct * 16 + mlane) * 32 + quad * 8];
        #pragma unroll
        for (int rt = 0; rt < 4; rt++)
            #pragma unroll
            for (int ct = 0; ct < 4; ct++)
                acc[rt][ct] = __builtin_amdgcn_mfma_f32_16x16x32_bf16(af[rt], bf[ct], acc[rt][ct], 0, 0, 0);
    }

    const int row0 = m0 + wr * 64 + quad * 4;
    const int col0 = n0 + wc * 64 + mlane;
    #pragma unroll
    for (int rt = 0; rt < 4; rt++)
        #pragma unroll
        for (int ct = 0; ct < 4; ct++) {
            int c = col0 + ct * 16;
            float bv = (!BF16OUT && bias != nullptr) ? bias[c] : 0.f;
            #pragma unroll
            for (int reg = 0; reg < 4; reg++) {
                int rr = row0 + rt * 16 + reg;
                float v = acc[rt][ct][reg] + bv;
                if (BF16OUT) ((u16*)Cout)[(size_t)rr * Nn + c] = f2b(v);
                else         ((float*)Cout)[(size_t)rr * Nn + c] = v;
            }
        }
}

// ---------------------------------------------------------------------------
// Column softmax stats via MFMA: invl[bh][j] = 1 / sum_i exp(scale * q_i.k_j)
// Block: (j-tile of 64 keys, bh). 4 waves sweep disjoint 64-query tiles.
// ---------------------------------------------------------------------------
__global__ __launch_bounds__(256) void attn_stats(const u16* __restrict__ qkvb,
                                                  float* __restrict__ invl) {
    __shared__ u16 kt[64 * 72];
    __shared__ u16 qt[4][64 * 72];
    __shared__ float red[4][64];

    const int tid = threadIdx.x;
    const int lane = tid & 63, wave = tid >> 6;
    const int mlane = lane & 15, quad = lane >> 4;
    const int bh = blockIdx.y, b = bh >> 4, h = bh & 15;
    const int j0 = blockIdx.x * 64;

    const u16* qbase = qkvb + (size_t)b * N_ * RS_ + h * DH_;
    const u16* kbase = qbase + HID_;

    // K tile: 64 keys x 64 dims = 512 x 16B chunks
    for (int idx = tid; idx < 512; idx += 256) {
        int r = idx >> 3, d8 = (idx & 7) * 8;
        *(u16x8*)&kt[r * 72 + d8] = *(const u16x8*)&kbase[(size_t)(j0 + r) * RS_ + d8];
    }
    __syncthreads();

    float colacc[4] = {0.f, 0.f, 0.f, 0.f};
    u16* qw = &qt[wave][0];

    for (int i0 = wave * 64; i0 < N_; i0 += 256) {
        // wave-private Q staging: 64x64 tile, 8 chunks/lane (same-wave LDS order)
        #pragma unroll
        for (int t = 0; t < 8; t++) {
            int rr = t * 8 + (lane >> 3), d8 = (lane & 7) * 8;
            *(u16x8*)&qw[rr * 72 + d8] = *(const u16x8*)&qbase[(size_t)(i0 + rr) * RS_ + d8];
        }
        f32x4 sc[4][4] = {};
        #pragma unroll
        for (int ks = 0; ks < 2; ks++) {
            bf16x8 af[4], bf[4];
            #pragma unroll
            for (int rt = 0; rt < 4; rt++)
                af[rt] = *(const bf16x8*)&qw[(rt * 16 + mlane) * 72 + ks * 32 + quad * 8];
            #pragma unroll
            for (int ct = 0; ct < 4; ct++)
                bf[ct] = *(const bf16x8*)&kt[(ct * 16 + mlane) * 72 + ks * 32 + quad * 8];
            #pragma unroll
            for (int rt = 0; rt < 4; rt++)
                #pragma unroll
                for (int ct = 0; ct < 4; ct++)
                    sc[rt][ct] = __builtin_amdgcn_mfma_f32_16x16x32_bf16(af[rt], bf[ct], sc[rt][ct], 0, 0, 0);
        }
        #pragma unroll
        for (int rt = 0; rt < 4; rt++)
            #pragma unroll
            for (int ct = 0; ct < 4; ct++)
                #pragma unroll
                for (int reg = 0; reg < 4; reg++)
                    colacc[ct] += __expf(sc[rt][ct][reg] * SCALE_);
    }

    #pragma unroll
    for (int ct = 0; ct < 4; ct++) {
        float v = colacc[ct];
        v += __shfl_xor(v, 16, 64);   // combine quads (rows quad*4+reg)
        v += __shfl_xor(v, 32, 64);
        if (quad == 0) red[wave][ct * 16 + mlane] = v;
    }
    __syncthreads();
    if (tid < 64) {
        float l = red[0][tid] + red[1][tid] + red[2][tid] + red[3][tid];
        invl[(size_t)bh * N_ + j0 + tid] = 1.0f / l;
    }
}

// ---------------------------------------------------------------------------
// Apply: y[i][h*64+d] = sum_j exp(scale*q_i.k_j)*invl_j * v[j][d], MFMA both
// matmuls, P round-trips through wave-private LDS rows (C-layout -> A-layout).
// Block: (i-tile of 64 queries, bh); wave w owns query rows [w*16, w*16+16).
// ---------------------------------------------------------------------------
__global__ __launch_bounds__(256) void attn_apply(const u16* __restrict__ qkvb,
                                                  const u16* __restrict__ vT,
                                                  const float* __restrict__ invl,
                                                  u16* __restrict__ yb) {
    __shared__ u16 qt[64 * 72];
    __shared__ u16 kt[64 * 72];
    __shared__ u16 vt[64 * 72];
    __shared__ u16 pt[64 * 72];
    __shared__ float linv[64];

    const int tid = threadIdx.x;
    const int lane = tid & 63, wave = tid >> 6;
    const int mlane = lane & 15, quad = lane >> 4;
    const int bh = blockIdx.y, b = bh >> 4, h = bh & 15;
    const int i0 = blockIdx.x * 64;

    const u16* qbase = qkvb + (size_t)b * N_ * RS_ + h * DH_;
    const u16* kbase = qbase + HID_;
    const u16* vbase = vT + (size_t)bh * DH_ * N_;

    // Q tile once: full 512 chunks
    for (int idx = tid; idx < 512; idx += 256) {
        int r = idx >> 3, d8 = (idx & 7) * 8;
        *(u16x8*)&qt[r * 72 + d8] = *(const u16x8*)&qbase[(size_t)(i0 + r) * RS_ + d8];
    }

    f32x4 yacc[4] = {};

    for (int j0 = 0; j0 < N_; j0 += 64) {
        __syncthreads();
        for (int idx = tid; idx < 512; idx += 256) {
            int r = idx >> 3, c8 = (idx & 7) * 8;
            *(u16x8*)&kt[r * 72 + c8] = *(const u16x8*)&kbase[(size_t)(j0 + r) * RS_ + c8];
            *(u16x8*)&vt[r * 72 + c8] = *(const u16x8*)&vbase[(size_t)r * N_ + j0 + c8];
        }
        if (tid < 64) linv[tid] = invl[(size_t)bh * N_ + j0 + tid];
        __syncthreads();

        // S rows [wave*16, wave*16+16) x 64 key cols
        f32x4 sc[4] = {};
        #pragma unroll
        for (int ks = 0; ks < 2; ks++) {
            bf16x8 aq = *(const bf16x8*)&qt[(wave * 16 + mlane) * 72 + ks * 32 + quad * 8];
            #pragma unroll
            for (int ct = 0; ct < 4; ct++) {
                bf16x8 bk = *(const bf16x8*)&kt[(ct * 16 + mlane) * 72 + ks * 32 + quad * 8];
                sc[ct] = __builtin_amdgcn_mfma_f32_16x16x32_bf16(aq, bk, sc[ct], 0, 0, 0);
            }
        }
        // P = exp(S*scale)*invl[col] -> bf16, wave-private pt rows
        #pragma unroll
        for (int ct = 0; ct < 4; ct++)
            #pragma unroll
            for (int reg = 0; reg < 4; reg++) {
                int col = ct * 16 + mlane;
                float p = __expf(sc[ct][reg] * SCALE_) * linv[col];
                pt[(wave * 16 + quad * 4 + reg) * 72 + col] = f2b(p);
            }
        // Y += P @ V  (B-operand from vT rows d)
        #pragma unroll
        for (int ks = 0; ks < 2; ks++) {
            bf16x8 ap = *(const bf16x8*)&pt[(wave * 16 + mlane) * 72 + ks * 32 + quad * 8];
            #pragma unroll
            for (int dt = 0; dt < 4; dt++) {
                bf16x8 bv = *(const bf16x8*)&vt[(dt * 16 + mlane) * 72 + ks * 32 + quad * 8];
                yacc[dt] = __builtin_amdgcn_mfma_f32_16x16x32_bf16(ap, bv, yacc[dt], 0, 0, 0);
            }
        }
    }

    const size_t yrow0 = (size_t)b * N_ + i0 + wave * 16 + quad * 4;
    #pragma unroll
    for (int dt = 0; dt < 4; dt++)
        #pragma unroll
        for (int reg = 0; reg < 4; reg++)
            yb[(yrow0 + reg) * HID_ + h * DH_ + dt * 16 + mlane] = f2b(yacc[dt][reg]);
}

// ---------------------------------------------------------------------------
extern "C" void kernel_launch(void* const* d_in, const int* in_sizes, int n_in,
                              void* d_out, int out_size, void* d_ws, size_t ws_size,
                              hipStream_t stream) {
    (void)in_sizes; (void)n_in; (void)out_size; (void)ws_size;

    const float* x     = (const float*)d_in[0];
    const float* w_qkv = (const float*)d_in[1];
    const float* w_out = (const float*)d_in[2];
    const float* b_out = (const float*)d_in[3];

    u16* xb    = (u16*)d_ws;                         // [8192][1024]
    u16* wqkvT = xb    + (size_t)8192 * 1024;        // [3072][1024]
    u16* woutT = wqkvT + (size_t)3072 * 1024;        // [1024][1024]
    u16* qkvb  = woutT + (size_t)1024 * 1024;        // [8192][3072]
    u16* vTb   = qkvb  + (size_t)8192 * 3072;        // [64][64][2048]
    u16* yb    = vTb   + (size_t)64 * 64 * 2048;     // [8192][1024]
    float* invl = (float*)(yb + (size_t)8192 * 1024);// [64][2048]

    cast_bf16<<<4096, 256, 0, stream>>>(x, xb, 8192 * 1024);
    transpose_cast<<<dim3(3072 / 64, 1024 / 64), 256, 0, stream>>>(w_qkv, wqkvT, 1024, 3072);
    transpose_cast<<<dim3(1024 / 64, 1024 / 64), 256, 0, stream>>>(w_out, woutT, 1024, 1024);

    gemm_bt<1><<<dim3(3072 / 128, 8192 / 128), 256, 0, stream>>>(
        xb, wqkvT, nullptr, qkvb, 8192, 3072, 1024);

    build_vT<<<dim3(N_ / 64, 64), 256, 0, stream>>>(qkvb, vTb);
    attn_stats<<<dim3(N_ / 64, 64), 256, 0, stream>>>(qkvb, invl);
    attn_apply<<<dim3(N_ / 64, 64), 256, 0, stream>>>(qkvb, vTb, invl, yb);

    gemm_bt<0><<<dim3(1024 / 128, 8192 / 128), 256, 0, stream>>>(
        yb, woutT, b_out, d_out, 8192, 1024, 1024);
}